// Round 9
// baseline (502.754 us; speedup 1.0000x reference)
//
#include <hip/hip_runtime.h>
#include <cstdint>
#include <cstddef>

// ---------------------------------------------------------------------------
// CrossAttention2D: out = softmax((rope(XqWq^T) rope(XkWk^T)^T)/8) (XvWv^T) Wo^T
// B=4, N=48*48=2304, E=1024, H=16, D=64. bf16 MFMA, fp32 accum.
// R13: (1) gemm_qk + gemm_v merged into gemm_qkv (tn 0..23, proj=tn>>3
//     selects A ptr / epilogue, all block-uniform; [Wq|Wk|Wv] and [q|k|v]
//     are contiguous in the carve) - one fewer launch + tail overlap.
//     (2) attn COMPUTE de-fenced: s_setprio removed (independent waves =
//     the m190 null regime; the volatile setprio calls were pinning phase
//     order) and restructured per-c2 so exp(c2=1) VALU can interleave with
//     PV(c2=0) MFMA. attn otherwise = R12 (128us verified: LDS-free,
//     reg-double-buffered, native exp2).
// ---------------------------------------------------------------------------

typedef __bf16 bf16x8 __attribute__((ext_vector_type(8)));
typedef __bf16 bf16x4 __attribute__((ext_vector_type(4)));
typedef _Float16 f16x4 __attribute__((ext_vector_type(4)));
typedef _Float16 f16x8 __attribute__((ext_vector_type(8)));
typedef float f32x4 __attribute__((ext_vector_type(4)));

constexpr int Bc = 4, Hc = 16, Nc = 2304, Ec = 1024, WPc = 48;
constexpr int BNc = Bc * Nc;  // 9216

__device__ __forceinline__ f32x4 mfma16(bf16x8 a, bf16x8 b, f32x4 c) {
  return __builtin_amdgcn_mfma_f32_16x16x32_bf16(a, b, c, 0, 0, 0);
}
__device__ __forceinline__ f32x4 mfmah32(f16x8 a, f16x8 b, f32x4 c) {
  return __builtin_amdgcn_mfma_f32_16x16x32_f16(a, b, c, 0, 0, 0);
}

#if __has_builtin(__builtin_amdgcn_exp2f)
#define EXP2F(x) __builtin_amdgcn_exp2f(x)
#else
#define EXP2F(x) exp2f(x)
#endif

#define GPTR(p) ((const __attribute__((address_space(1))) void*)(p))
#define LPTR(p) ((__attribute__((address_space(3))) void*)(p))

// ------------------- fp32 -> bf16 convert, all 7 arrays ---------------------
// dst layout (contiguous in ws): [Wq EE][Wk EE][Wv EE][Wo EE][q BNE][k BNE][v BNE]
__global__ __launch_bounds__(256) void cvt_all(
    const float* __restrict__ s0, const float* __restrict__ s1,
    const float* __restrict__ s2, const float* __restrict__ s3,
    const float* __restrict__ s4, const float* __restrict__ s5,
    const float* __restrict__ s6, __bf16* __restrict__ d) {
  const size_t EE = (size_t)Ec * Ec, BNE = (size_t)BNc * Ec;
  const size_t g = ((size_t)blockIdx.x * 256 + threadIdx.x) * 8;
  const float* s;
  size_t off;
  if (g < 4 * EE) {            // EE = 1<<20; boundaries are block-uniform
    const size_t a = g >> 20;
    off = g & (EE - 1);
    s = (a == 0) ? s0 : (a == 1) ? s1 : (a == 2) ? s2 : s3;
  } else {
    const size_t h = g - 4 * EE;
    const size_t a = h / BNE;
    off = h - a * BNE;
    s = (a == 0) ? s4 : (a == 1) ? s5 : s6;
  }
  float4 f0 = *(const float4*)(s + off);
  float4 f1 = *(const float4*)(s + off + 4);
  bf16x8 v;
  v[0] = (__bf16)f0.x; v[1] = (__bf16)f0.y; v[2] = (__bf16)f0.z; v[3] = (__bf16)f0.w;
  v[4] = (__bf16)f1.x; v[5] = (__bf16)f1.y; v[6] = (__bf16)f1.z; v[7] = (__bf16)f1.w;
  *(bf16x8*)(d + g) = v;
}

// ---------------- shared GEMM core: 128x128 tile, BK=32, 4 waves ------------
// R5 structure: single LDS buffer, global_load_lds staging, 2 barriers/K-step.
#define GEMM_CORE(APTR, WPTR, KDIM)                                             \
  __shared__ __align__(16) __bf16 As[128 * 32];                                 \
  __shared__ __align__(16) __bf16 Bs[128 * 32];                                 \
  const int t = threadIdx.x;                                                    \
  const int lane = t & 63, wave = t >> 6;                                       \
  const int wm = wave & 1, wn = wave >> 1;                                      \
  const int quad = lane >> 4, l15 = lane & 15;                                  \
  const int rowInC = lane >> 2, colC = (lane & 3) * 8;                          \
  const __bf16* Ab = (APTR) + (size_t)(tm * 128) * (KDIM);                      \
  const __bf16* Wb = (WPTR) + (size_t)(tn * 128) * (KDIM);                      \
  f32x4 zero = {0.f, 0.f, 0.f, 0.f};                                            \
  f32x4 acc[4][4];                                                              \
  for (int i = 0; i < 4; ++i)                                                   \
    for (int j = 0; j < 4; ++j) acc[i][j] = zero;                               \
  for (int kk = 0; kk < (KDIM); kk += 32) {                                     \
    _Pragma("unroll") for (int tch = 0; tch < 2; ++tch) {                       \
      const int ch = wave * 2 + tch;                                            \
      const int row = ch * 16 + rowInC;                                         \
      __builtin_amdgcn_global_load_lds(GPTR(Ab + (size_t)row * (KDIM) + kk + colC), \
                                       LPTR(As + ch * 512), 16, 0, 0);          \
      __builtin_amdgcn_global_load_lds(GPTR(Wb + (size_t)row * (KDIM) + kk + colC), \
                                       LPTR(Bs + ch * 512), 16, 0, 0);          \
    }                                                                           \
    __syncthreads();                                                            \
    bf16x8 af[4], bfg[4];                                                       \
    _Pragma("unroll") for (int i = 0; i < 4; ++i)                               \
        af[i] = *(const bf16x8*)(As + (wm * 64 + i * 16 + l15) * 32 + quad * 8);\
    _Pragma("unroll") for (int j = 0; j < 4; ++j)                               \
        bfg[j] = *(const bf16x8*)(Bs + (wn * 64 + j * 16 + l15) * 32 + quad * 8);\
    _Pragma("unroll") for (int i = 0; i < 4; ++i)                               \
      _Pragma("unroll") for (int j = 0; j < 4; ++j)                             \
        acc[i][j] = mfma16(af[i], bfg[j], acc[i][j]);                           \
    __syncthreads();                                                            \
  }                                                                             \
  const int m0 = tm * 128 + wm * 64;                                            \
  const int nb0 = tn * 128 + wn * 64;

// ---------------- GEMM 1: fused Q+K+V projection + RoPE + pack --------------
// Col tiles 0..7 -> Q (natural layout, rope), 8..15 -> K (fragment order +
// token bit-permutation, rope), 16..23 -> V (f16 fragment order, no rope).
// All selects are block-uniform. A = qkvb + proj*BNE; W rows are contiguous
// [Wq|Wk|Wv] so Wb = Wqkv + tn*128*K covers all three.
__global__ __launch_bounds__(256) void gemm_qkv(const __bf16* __restrict__ qkvb,
                                                const __bf16* __restrict__ Wqkv,
                                                const float* __restrict__ bq,
                                                const float* __restrict__ bk,
                                                const float* __restrict__ bv,
                                                __bf16* __restrict__ Qhp,
                                                __bf16* __restrict__ Khp,
                                                _Float16* __restrict__ Vtp,
                                                float qscale) {
  const int tn = blockIdx.x % 24;   // 24 col tiles over 3072
  const int tm = blockIdx.x / 24;   // 72 row tiles
  const int proj = tn >> 3;         // 0 = Q, 1 = K, 2 = V (block-uniform)
  const __bf16* Asel = qkvb + (size_t)proj * BNc * Ec;
  GEMM_CORE(Asel, Wqkv, Ec)

  const int h = (nb0 >> 6) & 15;
  if (proj == 2) {
    // ---- V epilogue: f16 fragment order (verified gemm_v path) ----
#pragma unroll
    for (int i = 0; i < 4; ++i) {
      const int m = m0 + i * 16 + quad * 4;
      const int b = m / Nc;
      const int ntok = m - b * Nc;
      const int t64 = ntok & 63;
      const int c2 = t64 >> 5, qf = (t64 >> 3) & 3, jf0 = t64 & 7;  // jf0 in {0,4}
      const size_t vbase = ((size_t)(b * Hc + h) * 36 + (ntok >> 6)) * 4096;
#pragma unroll
      for (int j = 0; j < 4; ++j) {
        const float bi = bv[(nb0 + j * 16 + l15) & 1023];
        f16x4 v;
#pragma unroll
        for (int r = 0; r < 4; ++r) v[r] = (_Float16)(acc[i][j][r] + bi);
        *(f16x4*)(Vtp + vbase +
                  (size_t)(((c2 * 4 + j) * 64 + qf * 16 + l15) * 8 + jf0)) = v;
      }
    }
    return;
  }

  // ---- Q/K epilogue: rope + pack (verified gemm_qk path) ----
  const float* bb = proj ? bk : bq;
  float bj[4];
#pragma unroll
  for (int j = 0; j < 4; ++j) bj[j] = bb[(nb0 + j * 16 + l15) & 1023];
  const float f = exp2f(-(float)l15 * 0.8304820237218406f);
  const int lo3 = l15 & 7, hi8 = l15 >> 3;
#pragma unroll
  for (int i = 0; i < 4; ++i) {
#pragma unroll
    for (int r = 0; r < 4; ++r) {
      const int m = m0 + i * 16 + quad * 4 + r;
      const int b = m / Nc;
      const int ntok = m - b * Nc;
      const int ph = ntok / WPc, pw = ntok - (ntok / WPc) * WPc;
      float sh, ch, sw, cw;
      __sincosf((float)ph * f, &sh, &ch);
      __sincosf((float)pw * f, &sw, &cw);
      const float x0 = acc[i][0][r] + bj[0];
      const float x1 = acc[i][1][r] + bj[1];
      const float x2 = acc[i][2][r] + bj[2];
      const float x3 = acc[i][3][r] + bj[3];
      const float y0 = x0 * ch - x1 * sh;
      const float y1 = x1 * ch + x0 * sh;
      const float y2 = x2 * cw - x3 * sw;
      const float y3 = x3 * cw + x2 * sw;
      if (proj == 0) {
        __bf16* Op = Qhp + ((size_t)(b * Hc + h) * Nc + ntok) * 64;
        Op[l15]      = (__bf16)(y0 * qscale);
        Op[l15 + 16] = (__bf16)(y1 * qscale);
        Op[l15 + 32] = (__bf16)(y2 * qscale);
        Op[l15 + 48] = (__bf16)(y3 * qscale);
      } else {
        const int t64 = ntok & 63;
        const int p64 = (t64 & 35) | ((t64 & 4) << 2) | ((t64 & 24) >> 1);
        __bf16* Kp = Khp + ((size_t)(b * Hc + h) * 36 + (ntok >> 6)) * 4096 +
                     (size_t)((((p64 >> 4) * 2) * 64 + hi8 * 16 + (p64 & 15)) * 8 + lo3);
        Kp[0]   = (__bf16)y0;   // d = l15       (ks=0, quad_f=hi8)
        Kp[256] = (__bf16)y1;   // d = 16 + l15  (ks=0, quad_f=2+hi8)
        Kp[512] = (__bf16)y2;   // d = 32 + l15  (ks=1, quad_f=hi8)
        Kp[768] = (__bf16)y3;   // d = 48 + l15  (ks=1, quad_f=2+hi8)
      }
    }
  }
}

// ---------------- GEMM 3: output projection, fp32 + bias --------------------
__global__ __launch_bounds__(256) void gemm_out(const __bf16* __restrict__ A,
                                                const __bf16* __restrict__ Wo,
                                                const float* __restrict__ bo,
                                                float* __restrict__ C) {
  const int tn = blockIdx.x & 7;
  const int tm = blockIdx.x >> 3;
  GEMM_CORE(A, Wo, Ec)

#pragma unroll
  for (int j = 0; j < 4; ++j) {
    const int n = nb0 + j * 16 + l15;
    const float bi = bo[n];
#pragma unroll
    for (int i = 0; i < 4; ++i) {
      const int m = m0 + i * 16 + quad * 4;
#pragma unroll
      for (int r = 0; r < 4; ++r) C[(size_t)(m + r) * Ec + n] = acc[i][j][r] + bi;
    }
  }
}

// --------------------------- flash attention (R13) --------------------------
// LDS-free, barrier-free, register double-buffered, de-fenced: no setprio,
// per-c2 exp->PV so VALU (exp of c2=1) interleaves with MFMA (PV of c2=0).
constexpr int TQ = 128, TK = 64, NT = Nc / TK;  // 18 q-tiles, 36 k-tiles

__global__ __launch_bounds__(256) void attn(const __bf16* __restrict__ Qh,
                                            const __bf16* __restrict__ Kf,
                                            const _Float16* __restrict__ Vf,
                                            __bf16* __restrict__ Om) {
  const int bh = blockIdx.x;
  const int t = threadIdx.x, wave = t >> 6, lane = t & 63;
  const int quad = lane >> 4, l15 = lane & 15;
  const int qbase = blockIdx.y * TQ + wave * 32;

  bf16x8 bq[2][2];
#pragma unroll
  for (int s = 0; s < 2; ++s)
#pragma unroll
    for (int ks = 0; ks < 2; ++ks)
      bq[s][ks] = *(const bf16x8*)(Qh + ((size_t)bh * Nc + qbase + s * 16 + l15) * 64 +
                                   ks * 32 + quad * 8);

  const __bf16* Kb = Kf + (size_t)bh * (NT * 4096) + (size_t)lane * 8;
  const _Float16* Vb = Vf + (size_t)bh * (NT * 4096) + (size_t)lane * 8;

  const f32x4 zero = {0.f, 0.f, 0.f, 0.f};
  f32x4 oacc[2][4] = {{zero, zero, zero, zero}, {zero, zero, zero, zero}};
  f32x4 osum[2] = {zero, zero};
  const f16x8 fones8 = {(_Float16)1.f, (_Float16)1.f, (_Float16)1.f, (_Float16)1.f,
                        (_Float16)1.f, (_Float16)1.f, (_Float16)1.f, (_Float16)1.f};

#define LOADKV(KF, VF, KT)                                                      \
  {                                                                             \
    _Pragma("unroll") for (int f = 0; f < 8; ++f)                               \
      KF[f] = *(const bf16x8*)(Kb + (size_t)(KT) * 4096 + f * 512);             \
    _Pragma("unroll") for (int f = 0; f < 8; ++f)                               \
      VF[f] = *(const f16x8*)(Vb + (size_t)(KT) * 4096 + f * 512);              \
  }

  // QK^T fragment (ct,ks) = KF[ct*2+ks]; sacc layout as in R10..R12.
  // PV fragment (c2,dt) = VF[c2*4+dt]; row-sums via ones-MFMA.
  // exp(c2) only needs sacc[*][2c2],[2c2+1] -> scheduler can overlap
  // exp(c2=1) with PV(c2=0) and the tail of QK.
#define COMPUTE(KF, VF)                                                         \
  {                                                                             \
    f32x4 sacc[2][4] = {{zero, zero, zero, zero}, {zero, zero, zero, zero}};    \
    _Pragma("unroll") for (int ks = 0; ks < 2; ++ks)                            \
      _Pragma("unroll") for (int ct = 0; ct < 4; ++ct) {                        \
        sacc[0][ct] = mfma16(KF[ct * 2 + ks], bq[0][ks], sacc[0][ct]);          \
        sacc[1][ct] = mfma16(KF[ct * 2 + ks], bq[1][ks], sacc[1][ct]);          \
      }                                                                         \
    _Pragma("unroll") for (int c2 = 0; c2 < 2; ++c2) {                          \
      f16x8 pf[2];                                                              \
      _Pragma("unroll") for (int s = 0; s < 2; ++s)                             \
        _Pragma("unroll") for (int r = 0; r < 4; ++r) {                         \
          pf[s][r]     = (_Float16)EXP2F(sacc[s][2 * c2][r]);                   \
          pf[s][4 + r] = (_Float16)EXP2F(sacc[s][2 * c2 + 1][r]);               \
        }                                                                       \
      _Pragma("unroll") for (int dt = 0; dt < 4; ++dt) {                        \
        oacc[0][dt] = mfmah32(VF[c2 * 4 + dt], pf[0], oacc[0][dt]);             \
        oacc[1][dt] = mfmah32(VF[c2 * 4 + dt], pf[1], oacc[1][dt]);             \
      }                                                                         \
      osum[0] = mfmah32(fones8, pf[0], osum[0]);                                \
      osum[1] = mfmah32(fones8, pf[1], osum[1]);                                \
    }                                                                           \
  }

  bf16x8 kfA[8], kfB[8];
  f16x8 vfA[8], vfB[8];
  LOADKV(kfA, vfA, 0)

#pragma unroll 1
  for (int kt = 0; kt < NT; kt += 2) {   // NT = 36, even
    LOADKV(kfB, vfB, kt + 1)
    COMPUTE(kfA, vfA)
    if (kt + 2 < NT) LOADKV(kfA, vfA, kt + 2)
    COMPUTE(kfB, vfB)
  }

  // ---- epilogue: rinv from ones-MFMA (all regs equal), normalize, store ----
  const int b = bh >> 4, h = bh & 15;
#pragma unroll
  for (int s = 0; s < 2; ++s) {
    const float rinv = 1.0f / osum[s][0];
    __bf16* Op = Om + ((size_t)b * Nc + qbase + s * 16 + l15) * Ec + h * 64 + quad * 4;
#pragma unroll
    for (int dt = 0; dt < 4; ++dt) {
      bf16x4 o;
#pragma unroll
      for (int r = 0; r < 4; ++r) o[r] = (__bf16)(oacc[s][dt][r] * rinv);
      *(bf16x4*)(Op + dt * 16) = o;
    }
  }
#undef LOADKV
#undef COMPUTE
}

// ---------------------------------------------------------------------------
extern "C" void kernel_launch(void* const* d_in, const int* in_sizes, int n_in,
                              void* d_out, int out_size, void* d_ws, size_t ws_size,
                              hipStream_t stream) {
  const float* q  = (const float*)d_in[0];
  const float* k  = (const float*)d_in[1];
  const float* v  = (const float*)d_in[2];
  const float* Wq = (const float*)d_in[3];
  const float* bq = (const float*)d_in[4];
  const float* Wk = (const float*)d_in[5];
  const float* bk = (const float*)d_in[6];
  const float* Wv = (const float*)d_in[7];
  const float* bv = (const float*)d_in[8];
  const float* Wo = (const float*)d_in[9];
  const float* bo = (const float*)d_in[10];
  float* out = (float*)d_out;

  const size_t EE = (size_t)Ec * Ec;          // 1 M elems
  const size_t BNE = (size_t)BNc * Ec;        // 9.4 M elems

  // workspace carve (~102 MB with aliasing). The first 4EE+3BNE bf16 elems
  // form one contiguous cvt_all destination: [Wq|Wk|Wv|Wo|q|k|v].
  // NOTE: gemm_qkv requires [Wq|Wk|Wv] row-contiguous and [q|k|v] contiguous.
  char* w = (char*)d_ws;
  __bf16* Wqkb = (__bf16*)w; w += 2 * EE * 2;  // W_q rows | W_k rows
  __bf16* Wvb  = (__bf16*)w; w += EE * 2;      // W_v rows (contiguous after Wk)
  __bf16* Wob  = (__bf16*)w; w += EE * 2;
  __bf16* qb   = (__bf16*)w; w += BNE * 2;
  __bf16* kb   = (__bf16*)w; w += BNE * 2;    // == qb + BNE
  __bf16* vb   = (__bf16*)w; w += BNE * 2;    // == kb + BNE
  __bf16* Qhp  = (__bf16*)w; w += BNE * 2;
  __bf16* Khp  = (__bf16*)w; w += BNE * 2;    // K fragment-packed (36*4096/bh)
  __bf16* Vfp  = (__bf16*)w; w += BNE * 2;    // V fragment-packed f16
  _Float16* Vtp = (_Float16*)Vfp;
  __bf16* Omp = qb;               // qb dead after gemm_qkv; attn writes here
  (void)Wvb;

  const dim3 blk(256);
  const dim3 gCvt((4 * EE + 3 * BNE) / 8 / 256);  // 15872
  const dim3 gQKV(24 * (BNc / 128));  // 1728
  const dim3 gG(8 * (BNc / 128));     // 576
  const dim3 gAttn(Bc * Hc, Nc / TQ); // (64, 18)

  cvt_all<<<gCvt, blk, 0, stream>>>(Wq, Wk, Wv, Wo, q, k, v, Wqkb);

  const float qscale = 0.125f * 1.44269504088896340736f;  // 1/sqrt(64) * log2(e)

  gemm_qkv<<<gQKV, blk, 0, stream>>>(qb, Wqkb, bq, bk, bv, Qhp, Khp, Vtp, qscale);
  attn<<<gAttn, blk, 0, stream>>>(Qhp, Khp, Vtp, Omp);
  gemm_out<<<gG, blk, 0, stream>>>(Omp, Wob, bo, out);
}

// Round 10
// 409.799 us; speedup vs baseline: 1.2268x; 1.2268x over previous
//
#include <hip/hip_runtime.h>
#include <cstdint>
#include <cstddef>

// ---------------------------------------------------------------------------
// CrossAttention2D: out = softmax((rope(XqWq^T) rope(XkWk^T)^T)/8) (XvWv^T) Wo^T
// B=4, N=48*48=2304, E=1024, H=16, D=64. bf16 MFMA, fp32 accum.
// R14 = R13's merged gemm_qkv (-15us verified) + R12's attn EXACTLY
//     (128us verified). R13's attn "de-fencing" regressed +94us: the
//     volatile s_setprio calls are scheduling anchors keeping the
//     double-buffer loads issued ahead of compute (VGPR 112->104 showed the
//     loads being re-sunk; VALU/MFMA busy times were unchanged, pure stall).
//     Do not remove them without a within-probe A/B.
// ---------------------------------------------------------------------------

typedef __bf16 bf16x8 __attribute__((ext_vector_type(8)));
typedef __bf16 bf16x4 __attribute__((ext_vector_type(4)));
typedef _Float16 f16x4 __attribute__((ext_vector_type(4)));
typedef _Float16 f16x8 __attribute__((ext_vector_type(8)));
typedef float f32x4 __attribute__((ext_vector_type(4)));

constexpr int Bc = 4, Hc = 16, Nc = 2304, Ec = 1024, WPc = 48;
constexpr int BNc = Bc * Nc;  // 9216

__device__ __forceinline__ f32x4 mfma16(bf16x8 a, bf16x8 b, f32x4 c) {
  return __builtin_amdgcn_mfma_f32_16x16x32_bf16(a, b, c, 0, 0, 0);
}
__device__ __forceinline__ f32x4 mfmah32(f16x8 a, f16x8 b, f32x4 c) {
  return __builtin_amdgcn_mfma_f32_16x16x32_f16(a, b, c, 0, 0, 0);
}

#if __has_builtin(__builtin_amdgcn_exp2f)
#define EXP2F(x) __builtin_amdgcn_exp2f(x)
#else
#define EXP2F(x) exp2f(x)
#endif

#define GPTR(p) ((const __attribute__((address_space(1))) void*)(p))
#define LPTR(p) ((__attribute__((address_space(3))) void*)(p))

// ------------------- fp32 -> bf16 convert, all 7 arrays ---------------------
// dst layout (contiguous in ws): [Wq EE][Wk EE][Wv EE][Wo EE][q BNE][k BNE][v BNE]
__global__ __launch_bounds__(256) void cvt_all(
    const float* __restrict__ s0, const float* __restrict__ s1,
    const float* __restrict__ s2, const float* __restrict__ s3,
    const float* __restrict__ s4, const float* __restrict__ s5,
    const float* __restrict__ s6, __bf16* __restrict__ d) {
  const size_t EE = (size_t)Ec * Ec, BNE = (size_t)BNc * Ec;
  const size_t g = ((size_t)blockIdx.x * 256 + threadIdx.x) * 8;
  const float* s;
  size_t off;
  if (g < 4 * EE) {            // EE = 1<<20; boundaries are block-uniform
    const size_t a = g >> 20;
    off = g & (EE - 1);
    s = (a == 0) ? s0 : (a == 1) ? s1 : (a == 2) ? s2 : s3;
  } else {
    const size_t h = g - 4 * EE;
    const size_t a = h / BNE;
    off = h - a * BNE;
    s = (a == 0) ? s4 : (a == 1) ? s5 : s6;
  }
  float4 f0 = *(const float4*)(s + off);
  float4 f1 = *(const float4*)(s + off + 4);
  bf16x8 v;
  v[0] = (__bf16)f0.x; v[1] = (__bf16)f0.y; v[2] = (__bf16)f0.z; v[3] = (__bf16)f0.w;
  v[4] = (__bf16)f1.x; v[5] = (__bf16)f1.y; v[6] = (__bf16)f1.z; v[7] = (__bf16)f1.w;
  *(bf16x8*)(d + g) = v;
}

// ---------------- shared GEMM core: 128x128 tile, BK=32, 4 waves ------------
// R5 structure: single LDS buffer, global_load_lds staging, 2 barriers/K-step.
#define GEMM_CORE(APTR, WPTR, KDIM)                                             \
  __shared__ __align__(16) __bf16 As[128 * 32];                                 \
  __shared__ __align__(16) __bf16 Bs[128 * 32];                                 \
  const int t = threadIdx.x;                                                    \
  const int lane = t & 63, wave = t >> 6;                                       \
  const int wm = wave & 1, wn = wave >> 1;                                      \
  const int quad = lane >> 4, l15 = lane & 15;                                  \
  const int rowInC = lane >> 2, colC = (lane & 3) * 8;                          \
  const __bf16* Ab = (APTR) + (size_t)(tm * 128) * (KDIM);                      \
  const __bf16* Wb = (WPTR) + (size_t)(tn * 128) * (KDIM);                      \
  f32x4 zero = {0.f, 0.f, 0.f, 0.f};                                            \
  f32x4 acc[4][4];                                                              \
  for (int i = 0; i < 4; ++i)                                                   \
    for (int j = 0; j < 4; ++j) acc[i][j] = zero;                               \
  for (int kk = 0; kk < (KDIM); kk += 32) {                                     \
    _Pragma("unroll") for (int tch = 0; tch < 2; ++tch) {                       \
      const int ch = wave * 2 + tch;                                            \
      const int row = ch * 16 + rowInC;                                         \
      __builtin_amdgcn_global_load_lds(GPTR(Ab + (size_t)row * (KDIM) + kk + colC), \
                                       LPTR(As + ch * 512), 16, 0, 0);          \
      __builtin_amdgcn_global_load_lds(GPTR(Wb + (size_t)row * (KDIM) + kk + colC), \
                                       LPTR(Bs + ch * 512), 16, 0, 0);          \
    }                                                                           \
    __syncthreads();                                                            \
    bf16x8 af[4], bfg[4];                                                       \
    _Pragma("unroll") for (int i = 0; i < 4; ++i)                               \
        af[i] = *(const bf16x8*)(As + (wm * 64 + i * 16 + l15) * 32 + quad * 8);\
    _Pragma("unroll") for (int j = 0; j < 4; ++j)                               \
        bfg[j] = *(const bf16x8*)(Bs + (wn * 64 + j * 16 + l15) * 32 + quad * 8);\
    _Pragma("unroll") for (int i = 0; i < 4; ++i)                               \
      _Pragma("unroll") for (int j = 0; j < 4; ++j)                             \
        acc[i][j] = mfma16(af[i], bfg[j], acc[i][j]);                           \
    __syncthreads();                                                            \
  }                                                                             \
  const int m0 = tm * 128 + wm * 64;                                            \
  const int nb0 = tn * 128 + wn * 64;

// ---------------- GEMM 1: fused Q+K+V projection + RoPE + pack --------------
// Col tiles 0..7 -> Q (natural layout, rope), 8..15 -> K (fragment order +
// token bit-permutation, rope), 16..23 -> V (f16 fragment order, no rope).
// All selects are block-uniform. A = qkvb + proj*BNE; W rows are contiguous
// [Wq|Wk|Wv] so Wb = Wqkv + tn*128*K covers all three.
__global__ __launch_bounds__(256) void gemm_qkv(const __bf16* __restrict__ qkvb,
                                                const __bf16* __restrict__ Wqkv,
                                                const float* __restrict__ bq,
                                                const float* __restrict__ bk,
                                                const float* __restrict__ bv,
                                                __bf16* __restrict__ Qhp,
                                                __bf16* __restrict__ Khp,
                                                _Float16* __restrict__ Vtp,
                                                float qscale) {
  const int tn = blockIdx.x % 24;   // 24 col tiles over 3072
  const int tm = blockIdx.x / 24;   // 72 row tiles
  const int proj = tn >> 3;         // 0 = Q, 1 = K, 2 = V (block-uniform)
  const __bf16* Asel = qkvb + (size_t)proj * BNc * Ec;
  GEMM_CORE(Asel, Wqkv, Ec)

  const int h = (nb0 >> 6) & 15;
  if (proj == 2) {
    // ---- V epilogue: f16 fragment order (verified gemm_v path) ----
#pragma unroll
    for (int i = 0; i < 4; ++i) {
      const int m = m0 + i * 16 + quad * 4;
      const int b = m / Nc;
      const int ntok = m - b * Nc;
      const int t64 = ntok & 63;
      const int c2 = t64 >> 5, qf = (t64 >> 3) & 3, jf0 = t64 & 7;  // jf0 in {0,4}
      const size_t vbase = ((size_t)(b * Hc + h) * 36 + (ntok >> 6)) * 4096;
#pragma unroll
      for (int j = 0; j < 4; ++j) {
        const float bi = bv[(nb0 + j * 16 + l15) & 1023];
        f16x4 v;
#pragma unroll
        for (int r = 0; r < 4; ++r) v[r] = (_Float16)(acc[i][j][r] + bi);
        *(f16x4*)(Vtp + vbase +
                  (size_t)(((c2 * 4 + j) * 64 + qf * 16 + l15) * 8 + jf0)) = v;
      }
    }
    return;
  }

  // ---- Q/K epilogue: rope + pack (verified gemm_qk path) ----
  const float* bb = proj ? bk : bq;
  float bj[4];
#pragma unroll
  for (int j = 0; j < 4; ++j) bj[j] = bb[(nb0 + j * 16 + l15) & 1023];
  const float f = exp2f(-(float)l15 * 0.8304820237218406f);
  const int lo3 = l15 & 7, hi8 = l15 >> 3;
#pragma unroll
  for (int i = 0; i < 4; ++i) {
#pragma unroll
    for (int r = 0; r < 4; ++r) {
      const int m = m0 + i * 16 + quad * 4 + r;
      const int b = m / Nc;
      const int ntok = m - b * Nc;
      const int ph = ntok / WPc, pw = ntok - (ntok / WPc) * WPc;
      float sh, ch, sw, cw;
      __sincosf((float)ph * f, &sh, &ch);
      __sincosf((float)pw * f, &sw, &cw);
      const float x0 = acc[i][0][r] + bj[0];
      const float x1 = acc[i][1][r] + bj[1];
      const float x2 = acc[i][2][r] + bj[2];
      const float x3 = acc[i][3][r] + bj[3];
      const float y0 = x0 * ch - x1 * sh;
      const float y1 = x1 * ch + x0 * sh;
      const float y2 = x2 * cw - x3 * sw;
      const float y3 = x3 * cw + x2 * sw;
      if (proj == 0) {
        __bf16* Op = Qhp + ((size_t)(b * Hc + h) * Nc + ntok) * 64;
        Op[l15]      = (__bf16)(y0 * qscale);
        Op[l15 + 16] = (__bf16)(y1 * qscale);
        Op[l15 + 32] = (__bf16)(y2 * qscale);
        Op[l15 + 48] = (__bf16)(y3 * qscale);
      } else {
        const int t64 = ntok & 63;
        const int p64 = (t64 & 35) | ((t64 & 4) << 2) | ((t64 & 24) >> 1);
        __bf16* Kp = Khp + ((size_t)(b * Hc + h) * 36 + (ntok >> 6)) * 4096 +
                     (size_t)((((p64 >> 4) * 2) * 64 + hi8 * 16 + (p64 & 15)) * 8 + lo3);
        Kp[0]   = (__bf16)y0;   // d = l15       (ks=0, quad_f=hi8)
        Kp[256] = (__bf16)y1;   // d = 16 + l15  (ks=0, quad_f=2+hi8)
        Kp[512] = (__bf16)y2;   // d = 32 + l15  (ks=1, quad_f=hi8)
        Kp[768] = (__bf16)y3;   // d = 48 + l15  (ks=1, quad_f=2+hi8)
      }
    }
  }
}

// ---------------- GEMM 3: output projection, fp32 + bias --------------------
__global__ __launch_bounds__(256) void gemm_out(const __bf16* __restrict__ A,
                                                const __bf16* __restrict__ Wo,
                                                const float* __restrict__ bo,
                                                float* __restrict__ C) {
  const int tn = blockIdx.x & 7;
  const int tm = blockIdx.x >> 3;
  GEMM_CORE(A, Wo, Ec)

#pragma unroll
  for (int j = 0; j < 4; ++j) {
    const int n = nb0 + j * 16 + l15;
    const float bi = bo[n];
#pragma unroll
    for (int i = 0; i < 4; ++i) {
      const int m = m0 + i * 16 + quad * 4;
#pragma unroll
      for (int r = 0; r < 4; ++r) C[(size_t)(m + r) * Ec + n] = acc[i][j][r] + bi;
    }
  }
}

// --------------------------- flash attention (R12 exact) --------------------
// LDS-free, barrier-free, register double-buffered. 4 independent waves x 32
// q-rows. Tile kt+1's 16 fragment loads (coalesced dwordx4, L2-resident) are
// issued before tile kt's compute; named A/B buffers keep all indexing static.
// The s_setprio fences double as scheduling anchors for the load pipeline --
// removing them re-sinks the loads and costs +94us (R13 post-mortem).
constexpr int TQ = 128, TK = 64, NT = Nc / TK;  // 18 q-tiles, 36 k-tiles

__global__ __launch_bounds__(256) void attn(const __bf16* __restrict__ Qh,
                                            const __bf16* __restrict__ Kf,
                                            const _Float16* __restrict__ Vf,
                                            __bf16* __restrict__ Om) {
  const int bh = blockIdx.x;
  const int t = threadIdx.x, wave = t >> 6, lane = t & 63;
  const int quad = lane >> 4, l15 = lane & 15;
  const int qbase = blockIdx.y * TQ + wave * 32;

  bf16x8 bq[2][2];
#pragma unroll
  for (int s = 0; s < 2; ++s)
#pragma unroll
    for (int ks = 0; ks < 2; ++ks)
      bq[s][ks] = *(const bf16x8*)(Qh + ((size_t)bh * Nc + qbase + s * 16 + l15) * 64 +
                                   ks * 32 + quad * 8);

  const __bf16* Kb = Kf + (size_t)bh * (NT * 4096) + (size_t)lane * 8;
  const _Float16* Vb = Vf + (size_t)bh * (NT * 4096) + (size_t)lane * 8;

  const f32x4 zero = {0.f, 0.f, 0.f, 0.f};
  f32x4 oacc[2][4] = {{zero, zero, zero, zero}, {zero, zero, zero, zero}};
  f32x4 osum[2] = {zero, zero};
  const f16x8 fones8 = {(_Float16)1.f, (_Float16)1.f, (_Float16)1.f, (_Float16)1.f,
                        (_Float16)1.f, (_Float16)1.f, (_Float16)1.f, (_Float16)1.f};

#define LOADKV(KF, VF, KT)                                                      \
  {                                                                             \
    _Pragma("unroll") for (int f = 0; f < 8; ++f)                               \
      KF[f] = *(const bf16x8*)(Kb + (size_t)(KT) * 4096 + f * 512);             \
    _Pragma("unroll") for (int f = 0; f < 8; ++f)                               \
      VF[f] = *(const f16x8*)(Vb + (size_t)(KT) * 4096 + f * 512);              \
  }

  // QK^T fragment (ct,ks) = KF[ct*2+ks]; sacc layout as in R10/R11.
  // PV fragment (c2,dt) = VF[c2*4+dt]; row-sums via ones-MFMA.
#define COMPUTE(KF, VF)                                                         \
  {                                                                             \
    f32x4 sacc[2][4] = {{zero, zero, zero, zero}, {zero, zero, zero, zero}};    \
    __builtin_amdgcn_s_setprio(1);                                              \
    _Pragma("unroll") for (int ks = 0; ks < 2; ++ks)                            \
      _Pragma("unroll") for (int ct = 0; ct < 4; ++ct) {                        \
        sacc[0][ct] = mfma16(KF[ct * 2 + ks], bq[0][ks], sacc[0][ct]);          \
        sacc[1][ct] = mfma16(KF[ct * 2 + ks], bq[1][ks], sacc[1][ct]);          \
      }                                                                         \
    __builtin_amdgcn_s_setprio(0);                                              \
    f16x8 pf[2][2];                                                             \
    _Pragma("unroll") for (int s = 0; s < 2; ++s)                               \
      _Pragma("unroll") for (int c2 = 0; c2 < 2; ++c2) {                        \
        _Pragma("unroll") for (int r = 0; r < 4; ++r) {                         \
          pf[s][c2][r]     = (_Float16)EXP2F(sacc[s][2 * c2][r]);               \
          pf[s][c2][4 + r] = (_Float16)EXP2F(sacc[s][2 * c2 + 1][r]);           \
        }                                                                       \
      }                                                                         \
    __builtin_amdgcn_s_setprio(1);                                              \
    _Pragma("unroll") for (int c2 = 0; c2 < 2; ++c2) {                          \
      _Pragma("unroll") for (int dt = 0; dt < 4; ++dt) {                        \
        oacc[0][dt] = mfmah32(VF[c2 * 4 + dt], pf[0][c2], oacc[0][dt]);         \
        oacc[1][dt] = mfmah32(VF[c2 * 4 + dt], pf[1][c2], oacc[1][dt]);         \
      }                                                                         \
      osum[0] = mfmah32(fones8, pf[0][c2], osum[0]);                            \
      osum[1] = mfmah32(fones8, pf[1][c2], osum[1]);                            \
    }                                                                           \
    __builtin_amdgcn_s_setprio(0);                                              \
  }

  bf16x8 kfA[8], kfB[8];
  f16x8 vfA[8], vfB[8];
  LOADKV(kfA, vfA, 0)

#pragma unroll 1
  for (int kt = 0; kt < NT; kt += 2) {   // NT = 36, even
    LOADKV(kfB, vfB, kt + 1)
    COMPUTE(kfA, vfA)
    if (kt + 2 < NT) LOADKV(kfA, vfA, kt + 2)
    COMPUTE(kfB, vfB)
  }

  // ---- epilogue: rinv from ones-MFMA (all regs equal), normalize, store ----
  const int b = bh >> 4, h = bh & 15;
#pragma unroll
  for (int s = 0; s < 2; ++s) {
    const float rinv = 1.0f / osum[s][0];
    __bf16* Op = Om + ((size_t)b * Nc + qbase + s * 16 + l15) * Ec + h * 64 + quad * 4;
#pragma unroll
    for (int dt = 0; dt < 4; ++dt) {
      bf16x4 o;
#pragma unroll
      for (int r = 0; r < 4; ++r) o[r] = (__bf16)(oacc[s][dt][r] * rinv);
      *(bf16x4*)(Op + dt * 16) = o;
    }
  }
#undef LOADKV
#undef COMPUTE
}

// ---------------------------------------------------------------------------
extern "C" void kernel_launch(void* const* d_in, const int* in_sizes, int n_in,
                              void* d_out, int out_size, void* d_ws, size_t ws_size,
                              hipStream_t stream) {
  const float* q  = (const float*)d_in[0];
  const float* k  = (const float*)d_in[1];
  const float* v  = (const float*)d_in[2];
  const float* Wq = (const float*)d_in[3];
  const float* bq = (const float*)d_in[4];
  const float* Wk = (const float*)d_in[5];
  const float* bk = (const float*)d_in[6];
  const float* Wv = (const float*)d_in[7];
  const float* bv = (const float*)d_in[8];
  const float* Wo = (const float*)d_in[9];
  const float* bo = (const float*)d_in[10];
  float* out = (float*)d_out;

  const size_t EE = (size_t)Ec * Ec;          // 1 M elems
  const size_t BNE = (size_t)BNc * Ec;        // 9.4 M elems

  // workspace carve (~102 MB with aliasing). The first 4EE+3BNE bf16 elems
  // form one contiguous cvt_all destination: [Wq|Wk|Wv|Wo|q|k|v].
  // NOTE: gemm_qkv requires [Wq|Wk|Wv] row-contiguous and [q|k|v] contiguous.
  char* w = (char*)d_ws;
  __bf16* Wqkb = (__bf16*)w; w += 2 * EE * 2;  // W_q rows | W_k rows
  __bf16* Wvb  = (__bf16*)w; w += EE * 2;      // W_v rows (contiguous after Wk)
  __bf16* Wob  = (__bf16*)w; w += EE * 2;
  __bf16* qb   = (__bf16*)w; w += BNE * 2;
  __bf16* kb   = (__bf16*)w; w += BNE * 2;    // == qb + BNE
  __bf16* vb   = (__bf16*)w; w += BNE * 2;    // == kb + BNE
  __bf16* Qhp  = (__bf16*)w; w += BNE * 2;
  __bf16* Khp  = (__bf16*)w; w += BNE * 2;    // K fragment-packed (36*4096/bh)
  __bf16* Vfp  = (__bf16*)w; w += BNE * 2;    // V fragment-packed f16
  _Float16* Vtp = (_Float16*)Vfp;
  __bf16* Omp = qb;               // qb dead after gemm_qkv; attn writes here
  (void)Wvb;

  const dim3 blk(256);
  const dim3 gCvt((4 * EE + 3 * BNE) / 8 / 256);  // 15872
  const dim3 gQKV(24 * (BNc / 128));  // 1728
  const dim3 gG(8 * (BNc / 128));     // 576
  const dim3 gAttn(Bc * Hc, Nc / TQ); // (64, 18)

  cvt_all<<<gCvt, blk, 0, stream>>>(Wq, Wk, Wv, Wo, q, k, v, Wqkb);

  const float qscale = 0.125f * 1.44269504088896340736f;  // 1/sqrt(64) * log2(e)

  gemm_qkv<<<gQKV, blk, 0, stream>>>(qb, Wqkb, bq, bk, bv, Qhp, Khp, Vtp, qscale);
  attn<<<gAttn, blk, 0, stream>>>(Qhp, Khp, Vtp, Omp);
  gemm_out<<<gG, blk, 0, stream>>>(Omp, Wob, bo, out);
}